// Round 1
// baseline (364.635 us; speedup 1.0000x reference)
//
#include <hip/hip_runtime.h>
#include <stdint.h>

typedef unsigned short u16;
typedef __attribute__((ext_vector_type(8))) short bf16x8;
typedef __attribute__((ext_vector_type(4))) float f32x4;

#define C_IN    64
#define K_OUT   128
#define HW      112
#define HW2     (HW * HW)   // 12544
#define CP      72          // padded channel pitch (bf16 elems): 16B-aligned rows, bank-spread
#define NW      114         // w' + 1 in [0,114): includes left/right zero pad
#define THREADS 256

// round-to-nearest-even fp32 -> bf16 (finite inputs)
__device__ __forceinline__ u16 f2bf(float f) {
  union { float f; uint32_t u; } x; x.f = f;
  return (u16)((x.u + 0x7FFFu + ((x.u >> 16) & 1u)) >> 16);
}

// OIHW fp32 weights -> bf16 wt[(rs*K_OUT + kout)*C_IN + c]  (c contiguous)
__global__ void prep_weights(const float* __restrict__ w, u16* __restrict__ wt) {
  int idx = blockIdx.x * 256 + threadIdx.x;
  if (idx >= K_OUT * C_IN * 9) return;
  int c    = idx & (C_IN - 1);
  int kout = (idx >> 6) & (K_OUT - 1);
  int rs   = idx >> 13;
  wt[idx] = f2bf(w[(kout * C_IN + c) * 9 + rs]);
}

__global__ __launch_bounds__(THREADS, 2) void conv3x3(
    const float* __restrict__ x, const u16* __restrict__ wt,
    const float* __restrict__ bias, float* __restrict__ out) {
  // X tile: [r][w'+1][c], bf16, c contiguous (pitch CP). 3*114*72*2 = 49248 B
  __shared__ u16 Xs[3][NW][CP];
  // W tile for current (r,s): [kout][c], bf16. 128*72*2 = 18432 B
  __shared__ u16 Ws[K_OUT][CP];

  const int tid = threadIdx.x;
  const int bid = blockIdx.x;
  const int n = bid / HW;
  const int h = bid % HW;

  // ---- zero X tile (provides w-pad columns and out-of-range h rows) ----
  {
    uint32_t* p = (uint32_t*)&Xs[0][0][0];
    const int tot = 3 * NW * CP / 2;  // 12312 dwords
    for (int i = tid; i < tot; i += THREADS) p[i] = 0u;
  }
  __syncthreads();

  // ---- stage X rows h-1..h+1 as bf16 ----
  const float* xn = x + (size_t)n * C_IN * HW2;
  for (int r = 0; r < 3; ++r) {
    int row = h + r - 1;
    if (row < 0 || row >= HW) continue;  // block-uniform
    const float* xrow = xn + (size_t)row * HW;
    for (int t = tid; t < 32 * 28; t += THREADS) {
      int w4 = t % 28;         // which float4 along w
      int cp = t / 28;         // channel pair
      int c  = cp * 2;
      float4 va = *(const float4*)(xrow + (size_t)c * HW2 + w4 * 4);
      float4 vb = *(const float4*)(xrow + (size_t)(c + 1) * HW2 + w4 * 4);
      int wb = 1 + w4 * 4;
      *(uint32_t*)&Xs[r][wb + 0][c] = (uint32_t)f2bf(va.x) | ((uint32_t)f2bf(vb.x) << 16);
      *(uint32_t*)&Xs[r][wb + 1][c] = (uint32_t)f2bf(va.y) | ((uint32_t)f2bf(vb.y) << 16);
      *(uint32_t*)&Xs[r][wb + 2][c] = (uint32_t)f2bf(va.z) | ((uint32_t)f2bf(vb.z) << 16);
      *(uint32_t*)&Xs[r][wb + 3][c] = (uint32_t)f2bf(va.w) | ((uint32_t)f2bf(vb.w) << 16);
    }
  }
  // first __syncthreads() inside the rs loop covers X staging completion

  const int lane = tid & 63;
  const int wave = tid >> 6;
  const int quad = lane >> 4;
  const int l15  = lane & 15;
  const int kb   = wave * 32;  // wave's kout base (32 channels per wave)

  f32x4 acc[2][7];
#pragma unroll
  for (int i = 0; i < 2; ++i)
#pragma unroll
    for (int j = 0; j < 7; ++j) acc[i][j] = (f32x4){0.f, 0.f, 0.f, 0.f};

  for (int rs = 0; rs < 9; ++rs) {
    const int r = rs / 3;
    const int s = rs % 3;

    __syncthreads();  // previous compute done (and, at rs=0, X staging done)
    {
      const u16* wsrc = wt + rs * (K_OUT * C_IN);
#pragma unroll
      for (int t8 = 0; t8 < (K_OUT * C_IN / 8) / THREADS; ++t8) {  // 4 iters
        int t = tid + t8 * THREADS;
        int kout = t >> 3;
        int cc = (t & 7) * 8;
        *(uint4*)&Ws[kout][cc] = *(const uint4*)(wsrc + t * 8);
      }
    }
    __syncthreads();

#pragma unroll
    for (int ch = 0; ch < 2; ++ch) {
      const int c0 = ch * 32 + quad * 8;
      // A fragments: A[m = l15][k = quad*8+j] -> Ws[kb + mt*16 + l15][c0..c0+7]
      bf16x8 a0 = *(const bf16x8*)&Ws[kb + l15][c0];
      bf16x8 a1 = *(const bf16x8*)&Ws[kb + 16 + l15][c0];
#pragma unroll
      for (int wt7 = 0; wt7 < 7; ++wt7) {
        // B fragment: B[k = quad*8+j][n = l15] -> Xs[r][w + s][c0..c0+7], w = wt7*16+l15
        bf16x8 b = *(const bf16x8*)&Xs[r][wt7 * 16 + l15 + s][c0];
        acc[0][wt7] = __builtin_amdgcn_mfma_f32_16x16x32_bf16(a0, b, acc[0][wt7], 0, 0, 0);
        acc[1][wt7] = __builtin_amdgcn_mfma_f32_16x16x32_bf16(a1, b, acc[1][wt7], 0, 0, 0);
      }
    }
  }

  // ---- epilogue: D row = quad*4 + reg (kout), col = l15 (w) ----
  float* on = out + (size_t)n * K_OUT * HW2 + (size_t)h * HW;
#pragma unroll
  for (int mt = 0; mt < 2; ++mt) {
#pragma unroll
    for (int rg = 0; rg < 4; ++rg) {
      const int kout = kb + mt * 16 + quad * 4 + rg;
      const float bv = bias[kout];
      float* orow = on + (size_t)kout * HW2;
#pragma unroll
      for (int wt7 = 0; wt7 < 7; ++wt7) {
        orow[wt7 * 16 + l15] = acc[mt][wt7][rg] + bv;
      }
    }
  }
}

extern "C" void kernel_launch(void* const* d_in, const int* in_sizes, int n_in,
                              void* d_out, int out_size, void* d_ws, size_t ws_size,
                              hipStream_t stream) {
  const float* x  = (const float*)d_in[0];
  const float* w  = (const float*)d_in[1];
  const float* bi = (const float*)d_in[2];
  float* out = (float*)d_out;
  u16* wt = (u16*)d_ws;  // needs 9*128*64*2 = 147456 B of scratch

  prep_weights<<<(K_OUT * C_IN * 9 + 255) / 256, 256, 0, stream>>>(w, wt);
  conv3x3<<<32 * HW, THREADS, 0, stream>>>(x, wt, bi, out);
}